// Round 2
// baseline (455.939 us; speedup 1.0000x reference)
//
#include <hip/hip_runtime.h>
#include <hip/hip_bf16.h>

// Fused RNN: h_t = tanh([x_t, h_{t-1}] @ W_cell + b_cell), t = 0..127, then
// logits = h_final @ W_out + b_out.
// fp32 in/out; bf16 MFMA with fp32 accumulate. One block = 16 batch rows;
// W resident in VGPRs; h double-buffered in LDS (bf16).
//
// R2 change: __launch_bounds__(320, 2). The declared resident state (wx+wh 72
// VGPR, X dbuf 64 VGPR, frags/accs ~60) needs ~200 VGPRs; the previous build
// allocated only 80 (compiler occupancy heuristic), forcing per-step
// rematerialization of the "resident" weights — the real critical path
// (~3750 cy/step vs ~500 fundamental). min-2-waves/EU caps at 256 VGPRs,
// which 1-block/CU (5 waves on 4 SIMDs) affords exactly.

typedef __bf16 bf16x8 __attribute__((ext_vector_type(8)));
typedef float  f32x4  __attribute__((ext_vector_type(4)));
typedef float  f32x8  __attribute__((ext_vector_type(8)));
typedef unsigned short u16;

#define B_  4096
#define T_  128
#define D_  128
#define H_  150
#define O_  10

#define KX 4        // 128 / 32
#define KH 5        // 160 / 32 (padded)
#define HPAD 168    // row stride: 336 B, keeps ds_read_b128 16B-aligned

__global__ __launch_bounds__(320, 2) void rnn_fused(
    const float* __restrict__ X,
    const float* __restrict__ Wc,
    const float* __restrict__ bc,
    const float* __restrict__ Wo,
    const float* __restrict__ bo,
    float* __restrict__ out)
{
    __shared__ __attribute__((aligned(16))) __bf16 sh_h[2][16][HPAD];

    const int tid  = threadIdx.x;
    const int wid  = tid >> 6;      // 0..4
    const int lane = tid & 63;
    const int q    = lane >> 4;     // 0..3
    const int l16  = lane & 15;
    const int row0 = blockIdx.x * 16;

    // ---- zero both h buffers ----
    {
        __bf16* p = &sh_h[0][0][0];
        for (int i = tid; i < 2 * 16 * HPAD; i += 320) p[i] = (__bf16)0.f;
    }

    // ---- preload W fragments (B-operand: B[k=q*8+i][n]) ----
    // Column mapping: col(nt, l16) = wid*32 + 2*l16 + nt  -> each lane's two
    // output columns are ADJACENT, so the epilogue writes one dword per row.
    bf16x8 wx[2][KX];
    bf16x8 wh[2][KH];
    float  bias[2];
    const int colw = wid * 32 + 2 * l16;          // 0..158 within padded 160
#pragma unroll
    for (int nt = 0; nt < 2; ++nt) {
        const int  j   = colw + nt;
        const bool jv  = (j < H_);
        const int  jcl = jv ? j : 0;
        bias[nt] = jv ? bc[jcl] : 0.f;
#pragma unroll
        for (int kt = 0; kt < KX; ++kt) {
            bf16x8 f;
#pragma unroll
            for (int i = 0; i < 8; ++i) {
                const int k = kt * 32 + q * 8 + i;               // < 128
                float v = Wc[k * H_ + jcl];
                v = fminf(fmaxf(v, -64.f), 64.f);                // one-time guard
                f[i] = jv ? (__bf16)v : (__bf16)0.f;
            }
            wx[nt][kt] = f;
        }
#pragma unroll
        for (int kt = 0; kt < KH; ++kt) {
            bf16x8 f;
#pragma unroll
            for (int i = 0; i < 8; ++i) {
                const int  kh  = kt * 32 + q * 8 + i;            // 0..159
                const bool kv  = jv && (kh < H_);
                const int  khc = (kh < H_) ? kh : 0;
                float v = Wc[(D_ + khc) * H_ + jcl];
                v = fminf(fmaxf(v, -64.f), 64.f);
                f[i] = kv ? (__bf16)v : (__bf16)0.f;
            }
            wh[nt][kt] = f;
        }
    }

    __syncthreads();

    // A-operand: lane holds A[m=l16][k = kt*32 + q*8 + i]
    const float* xrow = X + (size_t)(row0 + l16) * (T_ * D_) + q * 8;

    f32x8 xb0[KX], xb1[KX];
#pragma unroll
    for (int kt = 0; kt < KX; ++kt) xb0[kt] = *(const f32x8*)(xrow + 0 * D_ + kt * 32);
#pragma unroll
    for (int kt = 0; kt < KX; ++kt) xb1[kt] = *(const f32x8*)(xrow + 1 * D_ + kt * 32);

    auto step = [&](int t, f32x8 (&xb)[KX]) {
        // h fragments first: ds_read latency overlaps the cvt + x-MFMAs
        const __bf16 (*hb)[HPAD] = sh_h[t & 1];
        bf16x8 ah[KH];
#pragma unroll
        for (int kt = 0; kt < KH; ++kt)
            ah[kt] = *(const bf16x8*)(&hb[l16][kt * 32 + q * 8]);

        // convert X fragments fp32 -> bf16
        bf16x8 a[KX];
#pragma unroll
        for (int kt = 0; kt < KX; ++kt) {
#pragma unroll
            for (int i = 0; i < 8; ++i)
                a[kt][i] = (__bf16)xb[kt][i];
        }

        // prefetch X for t+2 into the just-consumed buffer; with the raw
        // barrier below these loads stay in flight across the next step.
        {
            int tt = t + 2; tt = (tt > T_ - 1) ? (T_ - 1) : tt;
#pragma unroll
            for (int kt = 0; kt < KX; ++kt)
                xb[kt] = *(const f32x8*)(xrow + (size_t)tt * D_ + kt * 32);
        }

        // split accumulators: x-chain (depth 4) and h-chain (depth 5), ILP 4
        f32x4 ax0 = {bias[0], bias[0], bias[0], bias[0]};
        f32x4 ax1 = {bias[1], bias[1], bias[1], bias[1]};
        f32x4 ah0 = {0.f, 0.f, 0.f, 0.f};
        f32x4 ah1 = {0.f, 0.f, 0.f, 0.f};
#pragma unroll
        for (int kt = 0; kt < KX; ++kt) {
            ax0 = __builtin_amdgcn_mfma_f32_16x16x32_bf16(a[kt], wx[0][kt], ax0, 0, 0, 0);
            ax1 = __builtin_amdgcn_mfma_f32_16x16x32_bf16(a[kt], wx[1][kt], ax1, 0, 0, 0);
        }
#pragma unroll
        for (int kt = 0; kt < KH; ++kt) {
            ah0 = __builtin_amdgcn_mfma_f32_16x16x32_bf16(ah[kt], wh[0][kt], ah0, 0, 0, 0);
            ah1 = __builtin_amdgcn_mfma_f32_16x16x32_bf16(ah[kt], wh[1][kt], ah1, 0, 0, 0);
        }

        // epilogue: tanh -> packed dword write (C layout: row=q*4+r, col pair)
        __bf16 (*ho)[HPAD] = sh_h[(t + 1) & 1];
#pragma unroll
        for (int r = 0; r < 4; ++r) {
            const float z0 = ax0[r] + ah0[r];
            const float z1 = ax1[r] + ah1[r];
            const float e0 = __builtin_amdgcn_exp2f(z0 * 2.8853900817779268f); // e^(2z)
            const float e1 = __builtin_amdgcn_exp2f(z1 * 2.8853900817779268f);
            const float h0 = 1.f - 2.f * __builtin_amdgcn_rcpf(e0 + 1.f);      // tanh
            const float h1 = 1.f - 2.f * __builtin_amdgcn_rcpf(e1 + 1.f);
            const unsigned p = (unsigned)__builtin_bit_cast(u16, (__bf16)h0)
                             | ((unsigned)__builtin_bit_cast(u16, (__bf16)h1) << 16);
            *(unsigned*)(&ho[q * 4 + r][colw]) = p;   // 4B-aligned, 2-way max
        }

        // lgkm-only fence + raw barrier: LDS writes made visible, but the
        // X prefetch (vmcnt, private VGPR dest) is NOT drained.
        asm volatile("s_waitcnt lgkmcnt(0)\n\ts_barrier" ::: "memory");
    };

    for (int t = 0; t < T_; t += 2) {
        step(t,     xb0);
        step(t + 1, xb1);
    }

    __syncthreads();

    // ---- classifier head: h_final lives in buffer (T_ & 1) == 0 ----
    if (tid < 16 * O_) {
        const int row = tid / O_;
        const int o   = tid - row * O_;
        float accv = bo[o];
        const __bf16* hf = &sh_h[0][row][0];
        for (int k = 0; k < H_; ++k)
            accv += (float)hf[k] * Wo[k * O_ + o];
        out[(size_t)(row0 + row) * O_ + o] = accv;
    }
}

extern "C" void kernel_launch(void* const* d_in, const int* in_sizes, int n_in,
                              void* d_out, int out_size, void* d_ws, size_t ws_size,
                              hipStream_t stream) {
    (void)in_sizes; (void)n_in; (void)out_size; (void)d_ws; (void)ws_size;
    const float* X  = (const float*)d_in[0];
    const float* Wc = (const float*)d_in[1];
    const float* bc = (const float*)d_in[2];
    const float* Wo = (const float*)d_in[3];
    const float* bo = (const float*)d_in[4];
    rnn_fused<<<dim3(B_ / 16), dim3(320), 0, stream>>>(X, Wc, bc, Wo, bo, (float*)d_out);
}

// Round 3
// 434.754 us; speedup vs baseline: 1.0487x; 1.0487x over previous
//
#include <hip/hip_runtime.h>
#include <hip/hip_bf16.h>

// Fused RNN: h_t = tanh([x_t, h_{t-1}] @ W_cell + b_cell), t = 0..127, then
// logits = h_final @ W_out + b_out.
// fp32 in/out; bf16 MFMA with fp32 accumulate. One block = 16 batch rows;
// W resident in registers; h double-buffered in LDS (bf16).
//
// R3 change: 5 waves -> 4 waves (256 thr), N-tiles split 3/3/2/2.
// With 5 waves on 4 SIMDs, one SIMD ran 2 waves and the per-step barrier made
// that SIMD the critical path (2x issue of MFMA+VALU+trans every step). 4
// waves = 1/SIMD evens the issue load and cuts the A-operand broadcast
// (all waves read full x and h every step) from 5x to 4x.
// Kept from R1: lgkm-only barrier (X prefetch stays in flight), split
// x/h accumulator chains, packed h writes (paired tiles), exp2-based tanh.

typedef __bf16 bf16x8 __attribute__((ext_vector_type(8)));
typedef float  f32x4  __attribute__((ext_vector_type(4)));
typedef float  f32x8  __attribute__((ext_vector_type(8)));
typedef unsigned short u16;

#define B_  4096
#define T_  128
#define D_  128
#define H_  150
#define O_  10

#define KX 4        // 128 / 32
#define KH 5        // 160 / 32 (padded)
#define HPAD 168    // row stride: 336 B, keeps ds_read_b128 16B-aligned

__global__ __launch_bounds__(256, 1) void rnn_fused(
    const float* __restrict__ X,
    const float* __restrict__ Wc,
    const float* __restrict__ bc,
    const float* __restrict__ Wo,
    const float* __restrict__ bo,
    float* __restrict__ out)
{
    __shared__ __attribute__((aligned(16))) __bf16 sh_h[2][16][HPAD];

    const int tid  = threadIdx.x;
    const int wid  = tid >> 6;      // 0..3
    const int lane = tid & 63;
    const int q    = lane >> 4;     // 0..3
    const int l16  = lane & 15;
    const int row0 = blockIdx.x * 16;

    // Tile assignment: 10 N-tiles of 16 cols over 4 waves: 3/3/2/2.
    const int nt_cnt = (wid < 2) ? 3 : 2;
    const int tbase  = (wid < 2) ? wid * 3 : 6 + (wid - 2) * 2;   // tile index
    const int cbase  = tbase * 16;                                 // col base

    // ---- zero both h buffers ----
    {
        __bf16* p = &sh_h[0][0][0];
        for (int i = tid; i < 2 * 16 * HPAD; i += 256) p[i] = (__bf16)0.f;
    }

    // Column mapping per lane:
    //   nt=0,1 : col = cbase + 2*l16 + nt   (pair -> one packed dword write)
    //   nt=2   : col = cbase + 32 + l16     (solo -> b16 writes)
    bf16x8 wx[3][KX];
    bf16x8 wh[3][KH];
    float  bias[3];
    int    jc[3];
#pragma unroll
    for (int nt = 0; nt < 3; ++nt) {
        if (nt >= nt_cnt) break;                    // wave-uniform
        const int  j   = (nt < 2) ? (cbase + 2 * l16 + nt) : (cbase + 32 + l16);
        const bool jv  = (j < H_);
        const int  jcl = jv ? j : 0;
        jc[nt]   = j;
        bias[nt] = jv ? bc[jcl] : 0.f;
#pragma unroll
        for (int kt = 0; kt < KX; ++kt) {
            bf16x8 f;
#pragma unroll
            for (int i = 0; i < 8; ++i) {
                const int k = kt * 32 + q * 8 + i;               // < 128
                float v = Wc[k * H_ + jcl];
                v = fminf(fmaxf(v, -64.f), 64.f);                // one-time guard
                f[i] = jv ? (__bf16)v : (__bf16)0.f;
            }
            wx[nt][kt] = f;
        }
#pragma unroll
        for (int kt = 0; kt < KH; ++kt) {
            bf16x8 f;
#pragma unroll
            for (int i = 0; i < 8; ++i) {
                const int  kh  = kt * 32 + q * 8 + i;            // 0..159
                const bool kv  = jv && (kh < H_);
                const int  khc = (kh < H_) ? kh : 0;
                float v = Wc[(D_ + khc) * H_ + jcl];
                v = fminf(fmaxf(v, -64.f), 64.f);
                f[i] = kv ? (__bf16)v : (__bf16)0.f;
            }
            wh[nt][kt] = f;
        }
    }

    __syncthreads();

    // A-operand: lane holds A[m=l16][k = kt*32 + q*8 + i]
    const float* xrow = X + (size_t)(row0 + l16) * (T_ * D_) + q * 8;

    f32x8 xb0[KX], xb1[KX];
#pragma unroll
    for (int kt = 0; kt < KX; ++kt) xb0[kt] = *(const f32x8*)(xrow + 0 * D_ + kt * 32);
#pragma unroll
    for (int kt = 0; kt < KX; ++kt) xb1[kt] = *(const f32x8*)(xrow + 1 * D_ + kt * 32);

    auto step = [&](int t, f32x8 (&xb)[KX]) {
        // h fragments first: ds_read latency overlaps the cvt + x-MFMAs
        const __bf16 (*hb)[HPAD] = sh_h[t & 1];
        bf16x8 ah[KH];
#pragma unroll
        for (int kt = 0; kt < KH; ++kt)
            ah[kt] = *(const bf16x8*)(&hb[l16][kt * 32 + q * 8]);

        // convert X fragments fp32 -> bf16
        bf16x8 a[KX];
#pragma unroll
        for (int kt = 0; kt < KX; ++kt) {
#pragma unroll
            for (int i = 0; i < 8; ++i)
                a[kt][i] = (__bf16)xb[kt][i];
        }

        // prefetch X for t+2 into the just-consumed buffer; the lgkm-only
        // barrier below keeps these in flight across the next step.
        {
            int tt = t + 2; tt = (tt > T_ - 1) ? (T_ - 1) : tt;
#pragma unroll
            for (int kt = 0; kt < KX; ++kt)
                xb[kt] = *(const f32x8*)(xrow + (size_t)tt * D_ + kt * 32);
        }

        // split accumulators: x-chains (depth 4) and h-chains (depth 5)
        f32x4 ax[3], ahh[3];
#pragma unroll
        for (int nt = 0; nt < 3; ++nt) {
            if (nt >= nt_cnt) break;
            ax[nt]  = (f32x4){bias[nt], bias[nt], bias[nt], bias[nt]};
            ahh[nt] = (f32x4){0.f, 0.f, 0.f, 0.f};
        }
#pragma unroll
        for (int kt = 0; kt < KX; ++kt) {
            ax[0] = __builtin_amdgcn_mfma_f32_16x16x32_bf16(a[kt], wx[0][kt], ax[0], 0, 0, 0);
            ax[1] = __builtin_amdgcn_mfma_f32_16x16x32_bf16(a[kt], wx[1][kt], ax[1], 0, 0, 0);
            if (nt_cnt == 3)
                ax[2] = __builtin_amdgcn_mfma_f32_16x16x32_bf16(a[kt], wx[2][kt], ax[2], 0, 0, 0);
        }
#pragma unroll
        for (int kt = 0; kt < KH; ++kt) {
            ahh[0] = __builtin_amdgcn_mfma_f32_16x16x32_bf16(ah[kt], wh[0][kt], ahh[0], 0, 0, 0);
            ahh[1] = __builtin_amdgcn_mfma_f32_16x16x32_bf16(ah[kt], wh[1][kt], ahh[1], 0, 0, 0);
            if (nt_cnt == 3)
                ahh[2] = __builtin_amdgcn_mfma_f32_16x16x32_bf16(ah[kt], wh[2][kt], ahh[2], 0, 0, 0);
        }

        // epilogue: tanh -> write (C layout: row=q*4+r, col per mapping above)
        __bf16 (*ho)[HPAD] = sh_h[(t + 1) & 1];
#pragma unroll
        for (int r = 0; r < 4; ++r) {
            const int rr = q * 4 + r;
            const float z0 = ax[0][r] + ahh[0][r];
            const float z1 = ax[1][r] + ahh[1][r];
            const float e0 = __builtin_amdgcn_exp2f(z0 * 2.8853900817779268f); // e^(2z)
            const float e1 = __builtin_amdgcn_exp2f(z1 * 2.8853900817779268f);
            const float h0 = 1.f - 2.f * __builtin_amdgcn_rcpf(e0 + 1.f);      // tanh
            const float h1 = 1.f - 2.f * __builtin_amdgcn_rcpf(e1 + 1.f);
            const unsigned p = (unsigned)__builtin_bit_cast(u16, (__bf16)h0)
                             | ((unsigned)__builtin_bit_cast(u16, (__bf16)h1) << 16);
            *(unsigned*)(&ho[rr][cbase + 2 * l16]) = p;   // 4B-aligned
            if (nt_cnt == 3) {
                const float z2 = ax[2][r] + ahh[2][r];
                const float e2 = __builtin_amdgcn_exp2f(z2 * 2.8853900817779268f);
                const float h2 = 1.f - 2.f * __builtin_amdgcn_rcpf(e2 + 1.f);
                ho[rr][cbase + 32 + l16] = (__bf16)h2;
            }
        }

        // lgkm-only fence + raw barrier: LDS writes made visible, but the
        // X prefetch (vmcnt, private VGPR dest) is NOT drained.
        asm volatile("s_waitcnt lgkmcnt(0)\n\ts_barrier" ::: "memory");
    };

    for (int t = 0; t < T_; t += 2) {
        step(t,     xb0);
        step(t + 1, xb1);
    }

    __syncthreads();

    // ---- classifier head: h_final lives in buffer (T_ & 1) == 0 ----
    if (tid < 16 * O_) {
        const int row = tid / O_;
        const int o   = tid - row * O_;
        float accv = bo[o];
        const __bf16* hf = &sh_h[0][row][0];
        for (int k = 0; k < H_; ++k)
            accv += (float)hf[k] * Wo[k * O_ + o];
        out[(size_t)(row0 + row) * O_ + o] = accv;
    }
}

extern "C" void kernel_launch(void* const* d_in, const int* in_sizes, int n_in,
                              void* d_out, int out_size, void* d_ws, size_t ws_size,
                              hipStream_t stream) {
    (void)in_sizes; (void)n_in; (void)out_size; (void)d_ws; (void)ws_size;
    const float* X  = (const float*)d_in[0];
    const float* Wc = (const float*)d_in[1];
    const float* bc = (const float*)d_in[2];
    const float* Wo = (const float*)d_in[3];
    const float* bo = (const float*)d_in[4];
    rnn_fused<<<dim3(B_ / 16), dim3(256), 0, stream>>>(X, Wc, bc, Wo, bo, (float*)d_out);
}

// Round 4
// 417.165 us; speedup vs baseline: 1.0929x; 1.0422x over previous
//
#include <hip/hip_runtime.h>
#include <hip/hip_bf16.h>

// Fused RNN: h_t = tanh([x_t, h_{t-1}] @ W_cell + b_cell), t = 0..127, then
// logits = h_final @ W_out + b_out.
//
// R4 restructure:
//  * 512 blocks x 256 thr, 8 batch rows/block -> 2 independent blocks per CU
//    (2 waves/SIMD). Blocks never share a barrier, so each fills the other's
//    latency bubbles (R3 measured ~2400 cy/step of unfillable stall at
//    1 wave/SIMD).
//  * X staged through LDS in bf16, converted ONCE per step (was: every wave
//    redundantly loaded + converted the full fp32 A-tile -> 32KB/step L1 and
//    ~130 VALU/wave). Pipeline: load t+3 to regs | hold 1 step | cvt+ds_write
//    t+2 | consume via ds_read_b128 A-frags. lgkm-only barrier keeps global
//    loads in flight across steps.
//  * A-operand rows: m=l16, real row = l16&7 (dup lanes broadcast free);
//    C rows 8-15 are duplicates -> only q<2 lanes write h.
//  * Weights stay register-resident (3/3/2/2 N-tile split, as R3).

typedef __bf16 bf16x8 __attribute__((ext_vector_type(8)));
typedef __bf16 bf16x4 __attribute__((ext_vector_type(4)));
typedef float  f32x4  __attribute__((ext_vector_type(4)));
typedef unsigned short u16;

#define B_  4096
#define T_  128
#define D_  128
#define H_  150
#define O_  10

#define KX 4        // 128 / 32
#define KH 5        // 160 / 32 (padded)
#define HPAD 168    // h row stride (elems): 336 B -> rows 20 banks apart, ~2-way max
#define XPAD 136    // x row stride (elems): 272 B -> rows 4 banks apart
#define ROWS 8

__global__ __launch_bounds__(256, 2) void rnn_fused(
    const float* __restrict__ X,
    const float* __restrict__ Wc,
    const float* __restrict__ bc,
    const float* __restrict__ Wo,
    const float* __restrict__ bo,
    float* __restrict__ out)
{
    __shared__ __attribute__((aligned(16))) __bf16 sh_h[2][ROWS][HPAD];
    __shared__ __attribute__((aligned(16))) __bf16 sh_x[3][ROWS][XPAD];

    const int tid  = threadIdx.x;
    const int wid  = tid >> 6;      // 0..3
    const int lane = tid & 63;
    const int q    = lane >> 4;     // 0..3
    const int l16  = lane & 15;
    const int arow = l16 & 7;       // real batch row within block for A-frags
    const int row0 = blockIdx.x * ROWS;

    // staging coords: one f32x4 per thread covers the 8x128 X tile
    const int srow = tid >> 5;          // 0..7
    const int scol = (tid & 31) * 4;    // 0..124

    // Tile assignment: 10 N-tiles of 16 cols over 4 waves: 3/3/2/2.
    const int nt_cnt = (wid < 2) ? 3 : 2;
    const int tbase  = (wid < 2) ? wid * 3 : 6 + (wid - 2) * 2;
    const int cbase  = tbase * 16;

    // ---- zero h buffers ----
    {
        __bf16* p = &sh_h[0][0][0];
        for (int i = tid; i < 2 * ROWS * HPAD; i += 256) p[i] = (__bf16)0.f;
    }

    // ---- preload W fragments (B-operand: B[k=q*8+i][n]) ----
    // col mapping: nt=0,1 -> cbase + 2*l16 + nt (paired dword write);
    //              nt=2   -> cbase + 32 + l16.
    // Cols >= H_ get zero weights + zero bias -> tanh(0)=0 -> h padding stays 0.
    bf16x8 wx[3][KX];
    bf16x8 wh[3][KH];
    float  bias[3];
#pragma unroll
    for (int nt = 0; nt < 3; ++nt) {
        if (nt >= nt_cnt) break;                    // wave-uniform
        const int  j   = (nt < 2) ? (cbase + 2 * l16 + nt) : (cbase + 32 + l16);
        const bool jv  = (j < H_);
        const int  jcl = jv ? j : 0;
        bias[nt] = jv ? bc[jcl] : 0.f;
#pragma unroll
        for (int kt = 0; kt < KX; ++kt) {
            bf16x8 f;
#pragma unroll
            for (int i = 0; i < 8; ++i) {
                const int k = kt * 32 + q * 8 + i;
                float v = Wc[k * H_ + jcl];
                v = fminf(fmaxf(v, -64.f), 64.f);
                f[i] = jv ? (__bf16)v : (__bf16)0.f;
            }
            wx[nt][kt] = f;
        }
#pragma unroll
        for (int kt = 0; kt < KH; ++kt) {
            bf16x8 f;
#pragma unroll
            for (int i = 0; i < 8; ++i) {
                const int  kh  = kt * 32 + q * 8 + i;
                const bool kv  = jv && (kh < H_);
                const int  khc = (kh < H_) ? kh : 0;
                float v = Wc[(D_ + khc) * H_ + jcl];
                v = fminf(fmaxf(v, -64.f), 64.f);
                f[i] = kv ? (__bf16)v : (__bf16)0.f;
            }
            wh[nt][kt] = f;
        }
    }

    // ---- prologue: stage X(0), X(1); preload X(2) into regs ----
    const float* Xg = X + (size_t)(row0 + srow) * (T_ * D_) + scol;
#pragma unroll
    for (int s = 0; s < 2; ++s) {
        f32x4 v = *(const f32x4*)(Xg + (size_t)s * D_);
        bf16x4 w;
#pragma unroll
        for (int i = 0; i < 4; ++i) w[i] = (__bf16)v[i];
        *(bf16x4*)(&sh_x[s][srow][scol]) = w;
    }
    f32x4 xl_cur = *(const f32x4*)(Xg + (size_t)2 * D_);

    __syncthreads();

    int cur = 0;                         // slot holding X(t)
    for (int t = 0; t < T_; ++t) {
        // A) issue global load for t+3 (stays in flight across the barrier)
        const int tt = (t + 3 < T_) ? (t + 3) : (T_ - 1);
        f32x4 xl_next = *(const f32x4*)(Xg + (size_t)tt * D_);

        // B) A-fragment reads (dup rows broadcast free)
        const __bf16* xb = &sh_x[cur][0][0];
        const __bf16* hb = &sh_h[t & 1][0][0];
        bf16x8 a[KX], ah[KH];
#pragma unroll
        for (int kt = 0; kt < KX; ++kt)
            a[kt] = *(const bf16x8*)(xb + arow * XPAD + kt * 32 + q * 8);
#pragma unroll
        for (int kt = 0; kt < KH; ++kt)
            ah[kt] = *(const bf16x8*)(hb + arow * HPAD + kt * 32 + q * 8);

        // C) MFMA: split x-chains (depth 4) and h-chains (depth 5)
        f32x4 ax[3], ahh[3];
#pragma unroll
        for (int nt = 0; nt < 3; ++nt) {
            if (nt >= nt_cnt) break;
            ax[nt]  = (f32x4){bias[nt], bias[nt], bias[nt], bias[nt]};
            ahh[nt] = (f32x4){0.f, 0.f, 0.f, 0.f};
        }
#pragma unroll
        for (int kt = 0; kt < KX; ++kt) {
            ax[0] = __builtin_amdgcn_mfma_f32_16x16x32_bf16(a[kt], wx[0][kt], ax[0], 0, 0, 0);
            ax[1] = __builtin_amdgcn_mfma_f32_16x16x32_bf16(a[kt], wx[1][kt], ax[1], 0, 0, 0);
            if (nt_cnt == 3)
                ax[2] = __builtin_amdgcn_mfma_f32_16x16x32_bf16(a[kt], wx[2][kt], ax[2], 0, 0, 0);
        }
#pragma unroll
        for (int kt = 0; kt < KH; ++kt) {
            ahh[0] = __builtin_amdgcn_mfma_f32_16x16x32_bf16(ah[kt], wh[0][kt], ahh[0], 0, 0, 0);
            ahh[1] = __builtin_amdgcn_mfma_f32_16x16x32_bf16(ah[kt], wh[1][kt], ahh[1], 0, 0, 0);
            if (nt_cnt == 3)
                ahh[2] = __builtin_amdgcn_mfma_f32_16x16x32_bf16(ah[kt], wh[2][kt], ahh[2], 0, 0, 0);
        }

        // D) stage write for t+2 (data loaded last step; ~1.7 steps of latency
        //    cover). Writes slot (cur+2)%3, which no wave reads this step.
        {
            const int wslot = (cur == 0) ? 2 : cur - 1;   // == (t+2)%3
            bf16x4 w;
#pragma unroll
            for (int i = 0; i < 4; ++i) w[i] = (__bf16)xl_cur[i];
            *(bf16x4*)(&sh_x[wslot][srow][scol]) = w;
            xl_cur = xl_next;
        }

        // E) tanh -> h[(t+1)&1]; only q<2 lanes hold real rows (0..7)
        __bf16 (*ho)[HPAD] = sh_h[(t + 1) & 1];
#pragma unroll
        for (int r = 0; r < 4; ++r) {
            const int rr = q * 4 + r;                      // 0..7 for q<2
            const float z0 = ax[0][r] + ahh[0][r];
            const float z1 = ax[1][r] + ahh[1][r];
            const float e0 = __builtin_amdgcn_exp2f(z0 * 2.8853900817779268f);
            const float e1 = __builtin_amdgcn_exp2f(z1 * 2.8853900817779268f);
            const float h0 = 1.f - 2.f * __builtin_amdgcn_rcpf(e0 + 1.f);
            const float h1 = 1.f - 2.f * __builtin_amdgcn_rcpf(e1 + 1.f);
            float h2 = 0.f;
            if (nt_cnt == 3) {
                const float z2 = ax[2][r] + ahh[2][r];
                const float e2 = __builtin_amdgcn_exp2f(z2 * 2.8853900817779268f);
                h2 = 1.f - 2.f * __builtin_amdgcn_rcpf(e2 + 1.f);
            }
            if (q < 2) {
                const unsigned p = (unsigned)__builtin_bit_cast(u16, (__bf16)h0)
                                 | ((unsigned)__builtin_bit_cast(u16, (__bf16)h1) << 16);
                *(unsigned*)(&ho[rr][cbase + 2 * l16]) = p;
                if (nt_cnt == 3)
                    ho[rr][cbase + 32 + l16] = (__bf16)h2;
            }
        }

        // F) lgkm-only fence + barrier: LDS visible, global prefetch in flight
        asm volatile("s_waitcnt lgkmcnt(0)\n\ts_barrier" ::: "memory");

        cur = (cur == 2) ? 0 : cur + 1;
    }

    __syncthreads();

    // ---- classifier head: h_final in sh_h[0] (T_ even) ----
    if (tid < ROWS * O_) {
        const int row = tid / O_;
        const int o   = tid - row * O_;
        float accv = bo[o];
        const __bf16* hf = &sh_h[0][row][0];
        for (int k = 0; k < H_; ++k)
            accv += (float)hf[k] * Wo[k * O_ + o];
        out[(size_t)(row0 + row) * O_ + o] = accv;
    }
}

extern "C" void kernel_launch(void* const* d_in, const int* in_sizes, int n_in,
                              void* d_out, int out_size, void* d_ws, size_t ws_size,
                              hipStream_t stream) {
    (void)in_sizes; (void)n_in; (void)out_size; (void)d_ws; (void)ws_size;
    const float* X  = (const float*)d_in[0];
    const float* Wc = (const float*)d_in[1];
    const float* bc = (const float*)d_in[2];
    const float* Wo = (const float*)d_in[3];
    const float* bo = (const float*)d_in[4];
    rnn_fused<<<dim3(B_ / ROWS), dim3(256), 0, stream>>>(X, Wc, bc, Wo, bo, (float*)d_out);
}

// Round 7
// 393.537 us; speedup vs baseline: 1.1586x; 1.0600x over previous
//
#include <hip/hip_runtime.h>
#include <hip/hip_bf16.h>

// Fused RNN: h_t = tanh([x_t, h_{t-1}] @ W_cell + b_cell), t = 0..127, then
// logits = h_final @ W_out + b_out.
//
// R7 = R5 structure with __syncthreads() instead of the inline-asm
// lgkm-only barrier (hedge after two container failures; plain barrier is the
// only conservative swap left — everything else is R4-proven).
// 256 blocks x 512 thr (8 waves), 16 REAL batch rows/block.
// R4 counters showed the step is issue-bound (VALU 45% + MFMA 29% + waits)
// with 2x duplicated work (8 rows in m=16 tiles); this halves issued work
// (90 MFMA/CU-step, tanh halved) at the same 2 waves/SIMD occupancy.
// N-split over 8 waves: w0..w5 -> tiles 0..5 (one 16-col tile, col=l16);
// w6 -> tiles {6,7}, w7 -> tiles {8,9} (paired cols 2*l16+nt -> packed dword
// h-writes).
// X staged via 3-slot bf16 LDS ring: load t+3 to regs | hold | cvt+write t+2
// | read t. Slot written at step t == slot last read at t-1, protected by the
// end-of-step barrier. Split x/h accumulator chains, exp2 tanh, W in regs.

typedef __bf16 bf16x8 __attribute__((ext_vector_type(8)));
typedef __bf16 bf16x4 __attribute__((ext_vector_type(4)));
typedef float  f32x4  __attribute__((ext_vector_type(4)));
typedef unsigned short u16;

#define B_  4096
#define T_  128
#define D_  128
#define H_  150
#define O_  10

#define KX 4        // 128 / 32
#define KH 5        // 160 / 32 (padded)
#define HPAD 168    // h row stride (elems): 336 B
#define XPAD 136    // x row stride (elems): 272 B (16B-aligned rows)
#define ROWS 16

__global__ __launch_bounds__(512, 2) void rnn_fused(
    const float* __restrict__ X,
    const float* __restrict__ Wc,
    const float* __restrict__ bc,
    const float* __restrict__ Wo,
    const float* __restrict__ bo,
    float* __restrict__ out)
{
    __shared__ __attribute__((aligned(16))) __bf16 sh_h[2][ROWS][HPAD];
    __shared__ __attribute__((aligned(16))) __bf16 sh_x[3][ROWS][XPAD];

    const int tid  = threadIdx.x;
    const int wid  = tid >> 6;      // 0..7
    const int lane = tid & 63;
    const int q    = lane >> 4;     // 0..3
    const int l16  = lane & 15;
    const int row0 = blockIdx.x * ROWS;

    // staging coords: one f32x4 per thread covers the 16x128 X tile
    const int srow = tid >> 5;          // 0..15
    const int scol = (tid & 31) * 4;    // 0..124

    // Tile assignment: w0..w5 one tile; w6 tiles {6,7}; w7 tiles {8,9}.
    const int nt_cnt = (wid < 6) ? 1 : 2;
    const int cbase  = (wid < 6) ? wid * 16 : ((wid == 6) ? 96 : 128);

    // ---- zero h buffers ----
    {
        __bf16* p = &sh_h[0][0][0];
        for (int i = tid; i < 2 * ROWS * HPAD; i += 512) p[i] = (__bf16)0.f;
    }

    // ---- preload W fragments (B-operand: B[k=q*8+i][n]) ----
    // col mapping: single-tile wave: j = cbase + l16
    //              2-tile wave:     j = cbase + 2*l16 + nt (paired)
    // Cols >= H_ get zero weights + zero bias -> tanh(0)=0 -> pad stays 0.
    bf16x8 wx[2][KX];
    bf16x8 wh[2][KH];
    float  bias[2];
#pragma unroll
    for (int nt = 0; nt < 2; ++nt) {
        if (nt >= nt_cnt) break;                    // wave-uniform
        const int  j   = (nt_cnt == 1) ? (cbase + l16) : (cbase + 2 * l16 + nt);
        const bool jv  = (j < H_);
        const int  jcl = jv ? j : 0;
        bias[nt] = jv ? bc[jcl] : 0.f;
#pragma unroll
        for (int kt = 0; kt < KX; ++kt) {
            bf16x8 f;
#pragma unroll
            for (int i = 0; i < 8; ++i) {
                const int k = kt * 32 + q * 8 + i;
                float v = Wc[k * H_ + jcl];
                v = fminf(fmaxf(v, -64.f), 64.f);
                f[i] = jv ? (__bf16)v : (__bf16)0.f;
            }
            wx[nt][kt] = f;
        }
#pragma unroll
        for (int kt = 0; kt < KH; ++kt) {
            bf16x8 f;
#pragma unroll
            for (int i = 0; i < 8; ++i) {
                const int  kh  = kt * 32 + q * 8 + i;
                const bool kv  = jv && (kh < H_);
                const int  khc = (kh < H_) ? kh : 0;
                float v = Wc[(D_ + khc) * H_ + jcl];
                v = fminf(fmaxf(v, -64.f), 64.f);
                f[i] = kv ? (__bf16)v : (__bf16)0.f;
            }
            wh[nt][kt] = f;
        }
    }

    // ---- prologue: stage X(0), X(1); preload X(2) into regs ----
    const float* Xg = X + (size_t)(row0 + srow) * (T_ * D_) + scol;
#pragma unroll
    for (int s = 0; s < 2; ++s) {
        f32x4 v = *(const f32x4*)(Xg + (size_t)s * D_);
        bf16x4 w;
#pragma unroll
        for (int i = 0; i < 4; ++i) w[i] = (__bf16)v[i];
        *(bf16x4*)(&sh_x[s][srow][scol]) = w;
    }
    f32x4 xl_cur = *(const f32x4*)(Xg + (size_t)2 * D_);

    __syncthreads();

    int cur = 0;                         // slot holding X(t)
    for (int t = 0; t < T_; ++t) {
        // A) issue global load for t+3
        const int tt = (t + 3 < T_) ? (t + 3) : (T_ - 1);
        f32x4 xl_next = *(const f32x4*)(Xg + (size_t)tt * D_);

        // B) A-fragment reads: A[m=l16][k = kt*32 + q*8 + i]
        const __bf16* xb = &sh_x[cur][0][0];
        const __bf16* hb = &sh_h[t & 1][0][0];
        bf16x8 a[KX], ah[KH];
#pragma unroll
        for (int kt = 0; kt < KX; ++kt)
            a[kt] = *(const bf16x8*)(xb + l16 * XPAD + kt * 32 + q * 8);
#pragma unroll
        for (int kt = 0; kt < KH; ++kt)
            ah[kt] = *(const bf16x8*)(hb + l16 * HPAD + kt * 32 + q * 8);

        // C) MFMA: split x-chains (depth 4) and h-chains (depth 5)
        f32x4 ax0 = (f32x4){bias[0], bias[0], bias[0], bias[0]};
        f32x4 ah0 = (f32x4){0.f, 0.f, 0.f, 0.f};
        f32x4 ax1 = (f32x4){bias[1], bias[1], bias[1], bias[1]};
        f32x4 ah1 = (f32x4){0.f, 0.f, 0.f, 0.f};
#pragma unroll
        for (int kt = 0; kt < KX; ++kt)
            ax0 = __builtin_amdgcn_mfma_f32_16x16x32_bf16(a[kt], wx[0][kt], ax0, 0, 0, 0);
#pragma unroll
        for (int kt = 0; kt < KH; ++kt)
            ah0 = __builtin_amdgcn_mfma_f32_16x16x32_bf16(ah[kt], wh[0][kt], ah0, 0, 0, 0);
        if (nt_cnt == 2) {
#pragma unroll
            for (int kt = 0; kt < KX; ++kt)
                ax1 = __builtin_amdgcn_mfma_f32_16x16x32_bf16(a[kt], wx[1][kt], ax1, 0, 0, 0);
#pragma unroll
            for (int kt = 0; kt < KH; ++kt)
                ah1 = __builtin_amdgcn_mfma_f32_16x16x32_bf16(ah[kt], wh[1][kt], ah1, 0, 0, 0);
        }

        // D) stage write for t+2 (data loaded last step; slot == slot last
        //    read at step t-1, safe past the end-of-step barrier)
        {
            const int wslot = (cur == 0) ? 2 : cur - 1;   // == (t+2)%3
            bf16x4 w;
#pragma unroll
            for (int i = 0; i < 4; ++i) w[i] = (__bf16)xl_cur[i];
            *(bf16x4*)(&sh_x[wslot][srow][scol]) = w;
            xl_cur = xl_next;
        }

        // E) tanh -> h[(t+1)&1]; all 16 C-rows real (row = q*4+r)
        __bf16 (*ho)[HPAD] = sh_h[(t + 1) & 1];
        if (nt_cnt == 1) {
#pragma unroll
            for (int r = 0; r < 4; ++r) {
                const float z0 = ax0[r] + ah0[r];
                const float e0 = __builtin_amdgcn_exp2f(z0 * 2.8853900817779268f);
                const float h0 = 1.f - 2.f * __builtin_amdgcn_rcpf(e0 + 1.f);
                ho[q * 4 + r][cbase + l16] = (__bf16)h0;
            }
        } else {
#pragma unroll
            for (int r = 0; r < 4; ++r) {
                const float z0 = ax0[r] + ah0[r];
                const float z1 = ax1[r] + ah1[r];
                const float e0 = __builtin_amdgcn_exp2f(z0 * 2.8853900817779268f);
                const float e1 = __builtin_amdgcn_exp2f(z1 * 2.8853900817779268f);
                const float h0 = 1.f - 2.f * __builtin_amdgcn_rcpf(e0 + 1.f);
                const float h1 = 1.f - 2.f * __builtin_amdgcn_rcpf(e1 + 1.f);
                const unsigned p = (unsigned)__builtin_bit_cast(u16, (__bf16)h0)
                                 | ((unsigned)__builtin_bit_cast(u16, (__bf16)h1) << 16);
                *(unsigned*)(&ho[q * 4 + r][cbase + 2 * l16]) = p;  // pad cols get 0
            }
        }

        // F) plain barrier (conservative: includes vmcnt drain)
        __syncthreads();

        cur = (cur == 2) ? 0 : cur + 1;
    }

    // ---- classifier head: h_final in sh_h[0] (T_ even) ----
    if (tid < ROWS * O_) {
        const int row = tid / O_;
        const int o   = tid - row * O_;
        float accv = bo[o];
        const __bf16* hf = &sh_h[0][row][0];
        for (int k = 0; k < H_; ++k)
            accv += (float)hf[k] * Wo[k * O_ + o];
        out[(size_t)(row0 + row) * O_ + o] = accv;
    }
}

extern "C" void kernel_launch(void* const* d_in, const int* in_sizes, int n_in,
                              void* d_out, int out_size, void* d_ws, size_t ws_size,
                              hipStream_t stream) {
    (void)in_sizes; (void)n_in; (void)out_size; (void)d_ws; (void)ws_size;
    const float* X  = (const float*)d_in[0];
    const float* Wc = (const float*)d_in[1];
    const float* bc = (const float*)d_in[2];
    const float* Wo = (const float*)d_in[3];
    const float* bo = (const float*)d_in[4];
    rnn_fused<<<dim3(B_ / ROWS), dim3(512), 0, stream>>>(X, Wc, bc, Wo, bo, (float*)d_out);
}